// Round 1
// baseline (1244.140 us; speedup 1.0000x reference)
//
#include <hip/hip_runtime.h>

#define BN_EPS 1e-5f

__device__ __forceinline__ int lower_bound_i(const int* a, int n, int key) {
    int lo = 0, hi = n;
    while (lo < hi) {
        int mid = (lo + hi) >> 1;
        if (a[mid] < key) lo = mid + 1; else hi = mid;
    }
    return lo;
}

// ---------------- CSR build ----------------
__global__ void count_deg_kernel(const int* __restrict__ u, int* __restrict__ deg, int E) {
    for (int e = blockIdx.x * blockDim.x + threadIdx.x; e < E; e += gridDim.x * blockDim.x)
        atomicAdd(&deg[u[e]], 1);
}

__global__ __launch_bounds__(1024) void scan_kernel(const int* __restrict__ deg,
                                                    int* __restrict__ row_start,
                                                    int* __restrict__ cursor,
                                                    int n, int total) {
    __shared__ int buf[1024];
    __shared__ int carry_s;
    if (threadIdx.x == 0) carry_s = 0;
    __syncthreads();
    for (int base = 0; base < n; base += 1024) {
        int i = base + threadIdx.x;
        int val = (i < n) ? deg[i] : 0;
        buf[threadIdx.x] = val;
        __syncthreads();
        for (int off = 1; off < 1024; off <<= 1) {
            int t = (threadIdx.x >= off) ? buf[threadIdx.x - off] : 0;
            __syncthreads();
            buf[threadIdx.x] += t;
            __syncthreads();
        }
        int carry = carry_s;
        int excl = buf[threadIdx.x] - val + carry;
        if (i < n) { row_start[i] = excl; cursor[i] = excl; }
        __syncthreads();
        if (threadIdx.x == 1023) carry_s = carry + buf[1023];
        __syncthreads();
    }
    if (threadIdx.x == 0) row_start[n] = total;
}

__global__ void fill_csr_kernel(const int* __restrict__ u, const int* __restrict__ c,
                                int* __restrict__ cursor, int* __restrict__ csr_src, int E) {
    for (int e = blockIdx.x * blockDim.x + threadIdx.x; e < E; e += gridDim.x * blockDim.x) {
        int pos = atomicAdd(&cursor[u[e]], 1);
        csr_src[pos] = c[e];
    }
}

// ---------------- aggregation: h2 = h + sum_{j->i} h[j] ----------------
__global__ __launch_bounds__(256) void aggregate_kernel(const float* __restrict__ h,
                                                        const int* __restrict__ row_start,
                                                        const int* __restrict__ csr_src,
                                                        float* __restrict__ h2, int N) {
    int node = blockIdx.x * 2 + (threadIdx.x >> 7);
    int d = threadIdx.x & 127;
    if (node >= N) return;
    int rs = row_start[node], re = row_start[node + 1];
    float acc = h[node * 128 + d];
    for (int e = rs; e < re; ++e) {
        int s = csr_src[e];
        acc += h[s * 128 + d];
    }
    h2[node * 128 + d] = acc;
}

// ---------------- fused GEMM (+ optional BN + ReLU) ----------------
// C[nrows, OUT] = act( bn( A[nrows, K] @ W[K, OUT] + bias ) )
// 256 threads, 32 rows per block, register tile RPT rows x 4 cols per thread.
template <int K, int OUT, bool BN>
__global__ __launch_bounds__(256) void gemm_kernel(const float* __restrict__ A,
                                                   const float* __restrict__ W,
                                                   const float* __restrict__ bias,
                                                   const float* __restrict__ gam,
                                                   const float* __restrict__ bet,
                                                   const float* __restrict__ mean,
                                                   const float* __restrict__ var,
                                                   float* __restrict__ C, int nrows) {
    constexpr int CG = OUT / 4;   // column groups (float4 per thread)
    constexpr int RG = 256 / CG;  // row groups
    constexpr int RPT = 32 / RG;  // rows per thread
    constexpr int K4 = K / 4;

    __shared__ float4 As[32][K4];

    const int tid = threadIdx.x;
    const int tx = tid % CG;
    const int ty = tid / CG;
    const int row0 = blockIdx.x * 32;

    // stage A tile (32 x K) into LDS, float4 coalesced
    const float4* A4 = (const float4*)A;
    for (int idx = tid; idx < 32 * K4; idx += 256) {
        int r = idx / K4, cc = idx % K4;
        int row = row0 + r;
        As[r][cc] = (row < nrows) ? A4[row * K4 + cc] : make_float4(0.f, 0.f, 0.f, 0.f);
    }
    __syncthreads();

    float4 acc[RPT];
#pragma unroll
    for (int r = 0; r < RPT; ++r) acc[r] = make_float4(0.f, 0.f, 0.f, 0.f);

    const float4* W4 = (const float4*)W;
#pragma unroll 4
    for (int k4 = 0; k4 < K4; ++k4) {
        float4 w0 = W4[(k4 * 4 + 0) * CG + tx];
        float4 w1 = W4[(k4 * 4 + 1) * CG + tx];
        float4 w2 = W4[(k4 * 4 + 2) * CG + tx];
        float4 w3 = W4[(k4 * 4 + 3) * CG + tx];
#pragma unroll
        for (int r = 0; r < RPT; ++r) {
            float4 a = As[ty * RPT + r][k4];
            acc[r].x += a.x * w0.x + a.y * w1.x + a.z * w2.x + a.w * w3.x;
            acc[r].y += a.x * w0.y + a.y * w1.y + a.z * w2.y + a.w * w3.y;
            acc[r].z += a.x * w0.z + a.y * w1.z + a.z * w2.z + a.w * w3.z;
            acc[r].w += a.x * w0.w + a.y * w1.w + a.z * w2.w + a.w * w3.w;
        }
    }

    // epilogue
    float4 bb = ((const float4*)bias)[tx];
    float4 sc = make_float4(1.f, 1.f, 1.f, 1.f);
    float4 sh = bb;
    if (BN) {
        float4 g = ((const float4*)gam)[tx];
        float4 bt = ((const float4*)bet)[tx];
        float4 mu = ((const float4*)mean)[tx];
        float4 vv = ((const float4*)var)[tx];
        sc.x = g.x * rsqrtf(vv.x + BN_EPS);
        sc.y = g.y * rsqrtf(vv.y + BN_EPS);
        sc.z = g.z * rsqrtf(vv.z + BN_EPS);
        sc.w = g.w * rsqrtf(vv.w + BN_EPS);
        sh.x = (bb.x - mu.x) * sc.x + bt.x;
        sh.y = (bb.y - mu.y) * sc.y + bt.y;
        sh.z = (bb.z - mu.z) * sc.z + bt.z;
        sh.w = (bb.w - mu.w) * sc.w + bt.w;
    }

    float4* C4 = (float4*)C;
#pragma unroll
    for (int r = 0; r < RPT; ++r) {
        int row = row0 + ty * RPT + r;
        if (row < nrows) {
            float4 y;
            if (BN) {
                y.x = fmaxf(acc[r].x * sc.x + sh.x, 0.f);
                y.y = fmaxf(acc[r].y * sc.y + sh.y, 0.f);
                y.z = fmaxf(acc[r].z * sc.z + sh.z, 0.f);
                y.w = fmaxf(acc[r].w * sc.w + sh.w, 0.f);
            } else {
                y.x = acc[r].x + sh.x;
                y.y = acc[r].y + sh.y;
                y.z = acc[r].z + sh.z;
                y.w = acc[r].w + sh.w;
            }
            C4[row * CG + tx] = y;
        }
    }
}

// ---------------- pooling over sorted batch ----------------
__global__ __launch_bounds__(128) void pool_kernel(const float* __restrict__ h,
                                                   const int* __restrict__ batch,
                                                   float* __restrict__ pooled, int N) {
    int g = blockIdx.x;
    int d = threadIdx.x;
    int s = lower_bound_i(batch, N, g);
    int e = lower_bound_i(batch, N, g + 1);
    float acc = 0.f;
    for (int r = s; r < e; ++r) acc += h[r * 128 + d];
    pooled[g * 128 + d] = acc;
}

// ---------------- readout MLP ----------------
__global__ __launch_bounds__(128) void readout_kernel(const float* __restrict__ pooled,
                                                      const float* __restrict__ Wr1,
                                                      const float* __restrict__ br1,
                                                      const float* __restrict__ Wr2,
                                                      const float* __restrict__ br2,
                                                      float* __restrict__ out) {
    __shared__ float prow[128];
    __shared__ float t[128];
    int g = blockIdx.x, j = threadIdx.x;
    prow[j] = pooled[g * 128 + j];
    __syncthreads();
    float acc = 0.f;
    for (int k = 0; k < 128; ++k) acc += prow[k] * Wr1[k * 128 + j];
    t[j] = fmaxf(acc + br1[j], 0.f);
    __syncthreads();
    if (j < 10) {
        float a2 = 0.f;
        for (int k = 0; k < 128; ++k) a2 += t[k] * Wr2[k * 10 + j];
        out[g * 10 + j] = a2 + br2[j];
    }
}

extern "C" void kernel_launch(void* const* d_in, const int* in_sizes, int n_in,
                              void* d_out, int out_size, void* d_ws, size_t ws_size,
                              hipStream_t stream) {
    const float* x   = (const float*)d_in[0];
    const int* c2    = (const int*)d_in[1];
    const int* u2    = (const int*)d_in[2];
    const int* batch = (const int*)d_in[3];
    const float* We  = (const float*)d_in[4];
    const float* be  = (const float*)d_in[5];
    const float* W1  = (const float*)d_in[6];
    const float* b1  = (const float*)d_in[7];
    const float* g1  = (const float*)d_in[8];
    const float* bt1 = (const float*)d_in[9];
    const float* m1  = (const float*)d_in[10];
    const float* v1  = (const float*)d_in[11];
    const float* W2  = (const float*)d_in[12];
    const float* b2  = (const float*)d_in[13];
    const float* g2  = (const float*)d_in[14];
    const float* bt2 = (const float*)d_in[15];
    const float* m2  = (const float*)d_in[16];
    const float* v2  = (const float*)d_in[17];
    const float* Wr1 = (const float*)d_in[18];
    const float* br1 = (const float*)d_in[19];
    const float* Wr2 = (const float*)d_in[20];
    const float* br2 = (const float*)d_in[21];

    const int N = in_sizes[3];       // 50000
    const int E = in_sizes[1];       // 800000
    const int L = in_sizes[7] / 256; // 3

    // workspace layout (bytes)
    char* ws = (char*)d_ws;
    size_t off = 0;
    float* h      = (float*)(ws + off); off += (size_t)N * 128 * 4;  // 25.6 MB
    float* h2     = (float*)(ws + off); off += (size_t)N * 128 * 4;  // 25.6 MB
    float* z      = (float*)(ws + off); off += (size_t)N * 256 * 4;  // 51.2 MB
    float* pooled = (float*)(ws + off); off += 64 * 128 * 4;
    int* deg      = (int*)(ws + off);   off += (size_t)N * 4;
    int* cursor   = (int*)(ws + off);   off += (size_t)N * 4;
    int* rowstart = (int*)(ws + off);   off += (size_t)(N + 1) * 4 + 252; off &= ~(size_t)255;
    int* csr_src  = (int*)(ws + off);   off += (size_t)E * 4;

    // ---- CSR build (u_2/c_2 are layer-invariant: build once per call) ----
    hipMemsetAsync(deg, 0, (size_t)N * 4, stream);
    count_deg_kernel<<<1024, 256, 0, stream>>>(u2, deg, E);
    scan_kernel<<<1, 1024, 0, stream>>>(deg, rowstart, cursor, N, E);
    fill_csr_kernel<<<1024, 256, 0, stream>>>(u2, c2, cursor, csr_src, E);

    const int gemm_blocks = (N + 31) / 32;

    // ---- embed: h = x @ We + be ----
    gemm_kernel<128, 128, false><<<gemm_blocks, 256, 0, stream>>>(
        x, We, be, nullptr, nullptr, nullptr, nullptr, h, N);

    // ---- GIN layers ----
    for (int l = 0; l < L; ++l) {
        aggregate_kernel<<<(N + 1) / 2, 256, 0, stream>>>(h, rowstart, csr_src, h2, N);
        gemm_kernel<128, 256, true><<<gemm_blocks, 256, 0, stream>>>(
            h2, W1 + (size_t)l * 128 * 256, b1 + l * 256, g1 + l * 256, bt1 + l * 256,
            m1 + l * 256, v1 + l * 256, z, N);
        gemm_kernel<256, 128, true><<<gemm_blocks, 256, 0, stream>>>(
            z, W2 + (size_t)l * 256 * 128, b2 + l * 128, g2 + l * 128, bt2 + l * 128,
            m2 + l * 128, v2 + l * 128, h, N);
    }

    // ---- pooling + readout ----
    pool_kernel<<<64, 128, 0, stream>>>(h, batch, pooled, N);
    readout_kernel<<<64, 128, 0, stream>>>(pooled, Wr1, br1, Wr2, br2, (float*)d_out);
}

// Round 2
// 596.713 us; speedup vs baseline: 2.0850x; 2.0850x over previous
//
#include <hip/hip_runtime.h>

#define BN_EPS 1e-5f

typedef __attribute__((ext_vector_type(8))) short bf16x8;
typedef __attribute__((ext_vector_type(4))) float f32x4;
typedef unsigned int uint32;
typedef unsigned short ushort16;

__device__ __forceinline__ unsigned short f2bf(float f) {
    unsigned u = __float_as_uint(f);
    u += 0x7FFFu + ((u >> 16) & 1u);   // round-to-nearest-even
    return (unsigned short)(u >> 16);
}
__device__ __forceinline__ float bf2f(unsigned short u) {
    return __uint_as_float((unsigned)u << 16);
}
__device__ __forceinline__ float lo_bf(uint32 u) { return __uint_as_float(u << 16); }
__device__ __forceinline__ float hi_bf(uint32 u) { return __uint_as_float(u & 0xFFFF0000u); }
__device__ __forceinline__ uint32 pack_bf(float a0, float a1) {
    return ((uint32)f2bf(a1) << 16) | (uint32)f2bf(a0);
}

__device__ __forceinline__ int lower_bound_i(const int* a, int n, int key) {
    int lo = 0, hi = n;
    while (lo < hi) {
        int mid = (lo + hi) >> 1;
        if (a[mid] < key) lo = mid + 1; else hi = mid;
    }
    return lo;
}

// ---------------- CSR build ----------------
__global__ void count_deg_kernel(const int* __restrict__ u, int* __restrict__ deg, int E) {
    for (int e = blockIdx.x * blockDim.x + threadIdx.x; e < E; e += gridDim.x * blockDim.x)
        atomicAdd(&deg[u[e]], 1);
}

__global__ __launch_bounds__(1024) void scan_kernel(const int* __restrict__ deg,
                                                    int* __restrict__ row_start,
                                                    int* __restrict__ cursor,
                                                    int n, int total) {
    __shared__ int buf[1024];
    __shared__ int carry_s;
    if (threadIdx.x == 0) carry_s = 0;
    __syncthreads();
    for (int base = 0; base < n; base += 1024) {
        int i = base + threadIdx.x;
        int val = (i < n) ? deg[i] : 0;
        buf[threadIdx.x] = val;
        __syncthreads();
        for (int off = 1; off < 1024; off <<= 1) {
            int t = (threadIdx.x >= off) ? buf[threadIdx.x - off] : 0;
            __syncthreads();
            buf[threadIdx.x] += t;
            __syncthreads();
        }
        int carry = carry_s;
        int excl = buf[threadIdx.x] - val + carry;
        if (i < n) { row_start[i] = excl; cursor[i] = excl; }
        __syncthreads();
        if (threadIdx.x == 1023) carry_s = carry + buf[1023];
        __syncthreads();
    }
    if (threadIdx.x == 0) row_start[n] = total;
}

__global__ void fill_csr_kernel(const int* __restrict__ u, const int* __restrict__ c,
                                int* __restrict__ cursor, int* __restrict__ csr_src, int E) {
    for (int e = blockIdx.x * blockDim.x + threadIdx.x; e < E; e += gridDim.x * blockDim.x) {
        int pos = atomicAdd(&cursor[u[e]], 1);
        csr_src[pos] = c[e];
    }
}

// ---------------- prep: f32 -> bf16 convert ----------------
__global__ void convert_bf16_kernel(const float* __restrict__ in, unsigned short* __restrict__ out, int n4) {
    int i = blockIdx.x * blockDim.x + threadIdx.x;
    if (i >= n4) return;
    float4 v = ((const float4*)in)[i];
    ushort4 o = make_ushort4(f2bf(v.x), f2bf(v.y), f2bf(v.z), f2bf(v.w));
    ((ushort4*)out)[i] = o;
}

// ---------------- prep: transpose W[K][OUT] f32 -> Wt[OUT][K] bf16 ----------------
__global__ void transpose_bf16_kernel(const float* __restrict__ in, unsigned short* __restrict__ out,
                                      int K, int OUT) {
    size_t base = (size_t)blockIdx.y * K * OUT;
    int idx = blockIdx.x * blockDim.x + threadIdx.x;
    if (idx >= K * OUT) return;
    int c = idx / K, k = idx % K;
    out[base + idx] = f2bf(in[base + (size_t)k * OUT + c]);
}

// ---------------- prep: fold BN into scale/shift ----------------
__global__ void bnprep_kernel(const float* __restrict__ bias, const float* __restrict__ g,
                              const float* __restrict__ bt, const float* __restrict__ m,
                              const float* __restrict__ v, float* __restrict__ scale,
                              float* __restrict__ shift, int n) {
    int l = blockIdx.y;
    int i = blockIdx.x * blockDim.x + threadIdx.x;
    if (i >= n) return;
    int o = l * n + i;
    if (g) {
        float sc = g[o] * rsqrtf(v[o] + BN_EPS);
        scale[o] = sc;
        shift[o] = (bias[o] - m[o]) * sc + bt[o];
    } else {
        scale[o] = 1.f;
        shift[o] = bias[o];
    }
}

// ---------------- aggregation: h2 = h + sum_{j->i} h[j]   (bf16 in/out, f32 accum) ----------------
__global__ __launch_bounds__(256) void aggregate_kernel(const unsigned short* __restrict__ h,
                                                        const int* __restrict__ row_start,
                                                        const int* __restrict__ csr_src,
                                                        unsigned short* __restrict__ h2, int N) {
    int node = blockIdx.x * 4 + (threadIdx.x >> 6);
    int lane = threadIdx.x & 63;
    if (node >= N) return;
    const uint32* hrow = (const uint32*)(h + (size_t)node * 128);
    uint32 s = hrow[lane];
    float a0 = lo_bf(s), a1 = hi_bf(s);
    int rs = row_start[node], re = row_start[node + 1];
    for (int e = rs; e < re; ++e) {
        const uint32* r = (const uint32*)(h + (size_t)csr_src[e] * 128);
        uint32 vv = r[lane];
        a0 += lo_bf(vv);
        a1 += hi_bf(vv);
    }
    ((uint32*)(h2 + (size_t)node * 128))[lane] = pack_bf(a0, a1);
}

// ---------------- MFMA GEMM: C = act(A[nrows,K] @ W[K,OUT] * scale + shift) ----------------
// A bf16 row-major, Wt bf16 [OUT][K] (pre-transposed). Swapped operands: lane holds
// C[r0 + (lane&15)][c0 + (lane>>4)*4 + t]  -> 8B packed stores per fragment.
template <int K, int OUT, bool RELU, bool OUT_BF16>
__global__ __launch_bounds__(256) void mfma_gemm_kernel(
    const unsigned short* __restrict__ A, const unsigned short* __restrict__ Wt,
    const float* __restrict__ scale, const float* __restrict__ shift,
    void* __restrict__ Cout, int nrows)
{
    constexpr int NT = OUT / 16;   // n-tiles of 16 cols
    constexpr int KS = K / 32;     // k-steps of 32
    constexpr int CH = OUT * K / 8; // 16B chunks of Wt
    __shared__ unsigned short WtLds[OUT * K];   // <= 64 KB

    const int tid = threadIdx.x;
    // stage Wt into LDS with XOR swizzle: byte ^= (row&7)<<4  (row = Wt row = C col)
    {
        const float4* src = (const float4*)Wt;
#pragma unroll
        for (int i = 0; i < CH / 256; ++i) {
            int c = tid + i * 256;
            int row = c / (K / 8);
            unsigned off = ((unsigned)c * 16u) ^ (((unsigned)row & 7u) << 4);
            *(float4*)((char*)WtLds + off) = src[c];
        }
    }
    __syncthreads();

    const int lane = tid & 63;
    const int l15 = lane & 15, lhi = lane >> 4;
    const int r = blockIdx.x * 64 + (tid >> 6) * 16 + l15;
    const int rr = (r < nrows) ? r : (nrows - 1);

    // B-operand fragments: this lane's A row, 8 contiguous bf16 per k-step
    bf16x8 bfrag[KS];
    const unsigned short* arow = A + (size_t)rr * K + lhi * 8;
#pragma unroll
    for (int ks = 0; ks < KS; ++ks)
        bfrag[ks] = *(const bf16x8*)(arow + ks * 32);

    f32x4 acc[NT];
#pragma unroll
    for (int nt = 0; nt < NT; ++nt) acc[nt] = (f32x4){0.f, 0.f, 0.f, 0.f};

#pragma unroll
    for (int ks = 0; ks < KS; ++ks) {
#pragma unroll
        for (int nt = 0; nt < NT; ++nt) {
            int row = nt * 16 + l15;
            unsigned off = ((unsigned)((row * K + ks * 32 + lhi * 8) * 2)) ^ (((unsigned)(l15 & 7u)) << 4);
            bf16x8 afrag = *(const bf16x8*)((const char*)WtLds + off);
            acc[nt] = __builtin_amdgcn_mfma_f32_16x16x32_bf16(afrag, bfrag[ks], acc[nt], 0, 0, 0);
        }
    }

    if (r >= nrows) return;
    const float4* sc4 = (const float4*)scale;
    const float4* sh4 = (const float4*)shift;
#pragma unroll
    for (int nt = 0; nt < NT; ++nt) {
        float4 sc = sc4[nt * 4 + lhi];
        float4 sh = sh4[nt * 4 + lhi];
        float y0 = acc[nt][0] * sc.x + sh.x;
        float y1 = acc[nt][1] * sc.y + sh.y;
        float y2 = acc[nt][2] * sc.z + sh.z;
        float y3 = acc[nt][3] * sc.w + sh.w;
        if (RELU) {
            y0 = fmaxf(y0, 0.f); y1 = fmaxf(y1, 0.f);
            y2 = fmaxf(y2, 0.f); y3 = fmaxf(y3, 0.f);
        }
        size_t o = (size_t)r * OUT + nt * 16 + lhi * 4;
        if constexpr (OUT_BF16) {
            ushort4 p = make_ushort4(f2bf(y0), f2bf(y1), f2bf(y2), f2bf(y3));
            *(ushort4*)((unsigned short*)Cout + o) = p;
        } else {
            *(float4*)((float*)Cout + o) = make_float4(y0, y1, y2, y3);
        }
    }
}

// ---------------- pooling over sorted batch: chunked + boundary atomics ----------------
__global__ __launch_bounds__(128) void pool_kernel(const unsigned short* __restrict__ h,
                                                   const int* __restrict__ batch,
                                                   float* __restrict__ pooled, int N, int chunk) {
    int d = threadIdx.x;
    int start = blockIdx.x * chunk;
    if (start >= N) return;
    int end = min(start + chunk, N);
    float acc = 0.f;
    int g = batch[start];
    for (int r = start; r < end; ++r) {
        int bg = batch[r];
        if (bg != g) {
            atomicAdd(&pooled[g * 128 + d], acc);
            acc = 0.f;
            g = bg;
        }
        acc += bf2f(h[(size_t)r * 128 + d]);
    }
    atomicAdd(&pooled[g * 128 + d], acc);
}

// ---------------- readout MLP ----------------
__global__ __launch_bounds__(128) void readout_kernel(const float* __restrict__ pooled,
                                                      const float* __restrict__ Wr1,
                                                      const float* __restrict__ br1,
                                                      const float* __restrict__ Wr2,
                                                      const float* __restrict__ br2,
                                                      float* __restrict__ out) {
    __shared__ float prow[128];
    __shared__ float t[128];
    int g = blockIdx.x, j = threadIdx.x;
    prow[j] = pooled[g * 128 + j];
    __syncthreads();
    float acc = 0.f;
    for (int k = 0; k < 128; ++k) acc += prow[k] * Wr1[k * 128 + j];
    t[j] = fmaxf(acc + br1[j], 0.f);
    __syncthreads();
    if (j < 10) {
        float a2 = 0.f;
        for (int k = 0; k < 128; ++k) a2 += t[k] * Wr2[k * 10 + j];
        out[g * 10 + j] = a2 + br2[j];
    }
}

extern "C" void kernel_launch(void* const* d_in, const int* in_sizes, int n_in,
                              void* d_out, int out_size, void* d_ws, size_t ws_size,
                              hipStream_t stream) {
    const float* x   = (const float*)d_in[0];
    const int* c2    = (const int*)d_in[1];
    const int* u2    = (const int*)d_in[2];
    const int* batch = (const int*)d_in[3];
    const float* We  = (const float*)d_in[4];
    const float* be  = (const float*)d_in[5];
    const float* W1  = (const float*)d_in[6];
    const float* b1  = (const float*)d_in[7];
    const float* g1  = (const float*)d_in[8];
    const float* bt1 = (const float*)d_in[9];
    const float* m1  = (const float*)d_in[10];
    const float* v1  = (const float*)d_in[11];
    const float* W2  = (const float*)d_in[12];
    const float* b2  = (const float*)d_in[13];
    const float* g2  = (const float*)d_in[14];
    const float* bt2 = (const float*)d_in[15];
    const float* m2  = (const float*)d_in[16];
    const float* v2  = (const float*)d_in[17];
    const float* Wr1 = (const float*)d_in[18];
    const float* br1 = (const float*)d_in[19];
    const float* Wr2 = (const float*)d_in[20];
    const float* br2 = (const float*)d_in[21];

    const int N = in_sizes[3];        // 50000
    const int E = in_sizes[1];        // 800000
    const int L = in_sizes[7] / 256;  // 3
    const int G = out_size / 10;      // 64

    // workspace layout (256B-aligned chunks)
    char* ws = (char*)d_ws;
    size_t off = 0;
    auto alloc = [&](size_t bytes) { char* p = ws + off; off += (bytes + 255) & ~(size_t)255; return p; };
    unsigned short* hb   = (unsigned short*)alloc((size_t)N * 128 * 2);
    unsigned short* h2b  = (unsigned short*)alloc((size_t)N * 128 * 2);
    unsigned short* zb   = (unsigned short*)alloc((size_t)N * 256 * 2);
    unsigned short* xb   = (unsigned short*)alloc((size_t)N * 128 * 2);
    unsigned short* Wte  = (unsigned short*)alloc(128 * 128 * 2);
    unsigned short* Wt1  = (unsigned short*)alloc((size_t)L * 256 * 128 * 2);
    unsigned short* Wt2  = (unsigned short*)alloc((size_t)L * 128 * 256 * 2);
    float* sce = (float*)alloc(128 * 4);
    float* she = (float*)alloc(128 * 4);
    float* sc1 = (float*)alloc((size_t)L * 256 * 4);
    float* sh1 = (float*)alloc((size_t)L * 256 * 4);
    float* sc2 = (float*)alloc((size_t)L * 128 * 4);
    float* sh2 = (float*)alloc((size_t)L * 128 * 4);
    float* pooled = (float*)alloc((size_t)G * 128 * 4);
    int* deg      = (int*)alloc((size_t)N * 4);
    int* cursor   = (int*)alloc((size_t)N * 4);
    int* rowstart = (int*)alloc((size_t)(N + 1) * 4);
    int* csr_src  = (int*)alloc((size_t)E * 4);

    // ---- CSR build ----
    hipMemsetAsync(deg, 0, (size_t)N * 4, stream);
    hipMemsetAsync(pooled, 0, (size_t)G * 128 * 4, stream);
    count_deg_kernel<<<1024, 256, 0, stream>>>(u2, deg, E);
    scan_kernel<<<1, 1024, 0, stream>>>(deg, rowstart, cursor, N, E);
    fill_csr_kernel<<<1024, 256, 0, stream>>>(u2, c2, cursor, csr_src, E);

    // ---- prep: converts / transposes / BN folds ----
    convert_bf16_kernel<<<(N * 128 / 4 + 255) / 256, 256, 0, stream>>>(x, xb, N * 128 / 4);
    transpose_bf16_kernel<<<dim3((128 * 128 + 255) / 256, 1), 256, 0, stream>>>(We, Wte, 128, 128);
    transpose_bf16_kernel<<<dim3((128 * 256 + 255) / 256, L), 256, 0, stream>>>(W1, Wt1, 128, 256);
    transpose_bf16_kernel<<<dim3((256 * 128 + 255) / 256, L), 256, 0, stream>>>(W2, Wt2, 256, 128);
    bnprep_kernel<<<dim3(1, 1), 256, 0, stream>>>(be, nullptr, nullptr, nullptr, nullptr, sce, she, 128);
    bnprep_kernel<<<dim3(1, L), 256, 0, stream>>>(b1, g1, bt1, m1, v1, sc1, sh1, 256);
    bnprep_kernel<<<dim3(1, L), 256, 0, stream>>>(b2, g2, bt2, m2, v2, sc2, sh2, 128);

    const int gemm_blocks = (N + 63) / 64;

    // ---- embed: h = x @ We + be ----
    mfma_gemm_kernel<128, 128, false, true><<<gemm_blocks, 256, 0, stream>>>(
        xb, Wte, sce, she, hb, N);

    // ---- GIN layers ----
    for (int l = 0; l < L; ++l) {
        aggregate_kernel<<<(N + 3) / 4, 256, 0, stream>>>(hb, rowstart, csr_src, h2b, N);
        mfma_gemm_kernel<128, 256, true, true><<<gemm_blocks, 256, 0, stream>>>(
            h2b, Wt1 + (size_t)l * 128 * 256, sc1 + l * 256, sh1 + l * 256, zb, N);
        mfma_gemm_kernel<256, 128, true, true><<<gemm_blocks, 256, 0, stream>>>(
            zb, Wt2 + (size_t)l * 256 * 128, sc2 + l * 128, sh2 + l * 128, hb, N);
    }

    // ---- pooling + readout ----
    const int chunk = (N + 511) / 512;
    pool_kernel<<<512, 128, 0, stream>>>(hb, batch, pooled, N, chunk);
    readout_kernel<<<G, 128, 0, stream>>>(pooled, Wr1, br1, Wr2, br2, (float*)d_out);
}

// Round 3
// 369.067 us; speedup vs baseline: 3.3710x; 1.6168x over previous
//
#include <hip/hip_runtime.h>

#define BN_EPS 1e-5f

typedef __attribute__((ext_vector_type(8))) short bf16x8;
typedef __attribute__((ext_vector_type(4))) float f32x4;
typedef unsigned int uint32;

__device__ __forceinline__ unsigned short f2bf(float f) {
    unsigned u = __float_as_uint(f);
    u += 0x7FFFu + ((u >> 16) & 1u);   // round-to-nearest-even
    return (unsigned short)(u >> 16);
}
__device__ __forceinline__ float bf2f(unsigned short u) {
    return __uint_as_float((unsigned)u << 16);
}
__device__ __forceinline__ float lo_bf(uint32 u) { return __uint_as_float(u << 16); }
__device__ __forceinline__ float hi_bf(uint32 u) { return __uint_as_float(u & 0xFFFF0000u); }
__device__ __forceinline__ uint32 pack_bf(float a0, float a1) {
    return ((uint32)f2bf(a1) << 16) | (uint32)f2bf(a0);
}

// ---------------- init: zero deg + pooled ----------------
__global__ void init_kernel(int* __restrict__ deg, float* __restrict__ pooled, int N, int GP) {
    int i = blockIdx.x * 256 + threadIdx.x;
    if (i < N) deg[i] = 0;
    if (i < GP) pooled[i] = 0.f;
}

// ---------------- CSR build ----------------
__global__ void count_deg_kernel(const int* __restrict__ u, int* __restrict__ deg, int E) {
    for (int e = blockIdx.x * blockDim.x + threadIdx.x; e < E; e += gridDim.x * blockDim.x)
        atomicAdd(&deg[u[e]], 1);
}

// hierarchical exclusive scan: local tile scans
__global__ __launch_bounds__(256) void scan_local_kernel(const int* __restrict__ deg,
                                                         int* __restrict__ row_start,
                                                         int* __restrict__ partials, int n) {
    __shared__ int buf[256];
    int i = blockIdx.x * 256 + threadIdx.x;
    int v = (i < n) ? deg[i] : 0;
    buf[threadIdx.x] = v;
    __syncthreads();
    for (int off = 1; off < 256; off <<= 1) {
        int t = (threadIdx.x >= off) ? buf[threadIdx.x - off] : 0;
        __syncthreads();
        buf[threadIdx.x] += t;
        __syncthreads();
    }
    if (i < n) row_start[i] = buf[threadIdx.x] - v;   // local exclusive
    if (threadIdx.x == 255) partials[blockIdx.x] = buf[255];
}

// scan the per-block partials (nb <= 256)
__global__ __launch_bounds__(256) void scan_partials_kernel(int* __restrict__ partials, int nb) {
    __shared__ int buf[256];
    int v = (threadIdx.x < nb) ? partials[threadIdx.x] : 0;
    buf[threadIdx.x] = v;
    __syncthreads();
    for (int off = 1; off < 256; off <<= 1) {
        int t = (threadIdx.x >= off) ? buf[threadIdx.x - off] : 0;
        __syncthreads();
        buf[threadIdx.x] += t;
        __syncthreads();
    }
    if (threadIdx.x < nb) partials[threadIdx.x] = buf[threadIdx.x] - v;  // exclusive
}

// add block offsets; also emit cursor copy and row_start[n]
__global__ __launch_bounds__(256) void scan_add_kernel(int* __restrict__ row_start,
                                                       int* __restrict__ cursor,
                                                       const int* __restrict__ partials,
                                                       int n, int total) {
    int i = blockIdx.x * 256 + threadIdx.x;
    if (i < n) {
        int v = row_start[i] + partials[blockIdx.x];
        row_start[i] = v;
        cursor[i] = v;
    } else if (i == n) {
        row_start[n] = total;
    }
}

__global__ void fill_csr_kernel(const int* __restrict__ u, const int* __restrict__ c,
                                int* __restrict__ cursor, int* __restrict__ csr_src, int E) {
    for (int e = blockIdx.x * blockDim.x + threadIdx.x; e < E; e += gridDim.x * blockDim.x) {
        int pos = atomicAdd(&cursor[u[e]], 1);
        csr_src[pos] = c[e];
    }
}

// ---------------- prep: all weight transposes, f32 -> bf16 [OUT][K] ----------------
__global__ void transpose_all_kernel(const float* __restrict__ We, const float* __restrict__ W1,
                                     const float* __restrict__ W2,
                                     unsigned short* __restrict__ Wte,
                                     unsigned short* __restrict__ Wt1,
                                     unsigned short* __restrict__ Wt2, int L) {
    int y = blockIdx.y;
    const float* src;
    unsigned short* dst;
    int K, OUT;
    if (y == 0)      { src = We; dst = Wte; K = 128; OUT = 128; }
    else if (y <= L) { int l = y - 1;     src = W1 + (size_t)l * 128 * 256; dst = Wt1 + (size_t)l * 128 * 256; K = 128; OUT = 256; }
    else             { int l = y - L - 1; src = W2 + (size_t)l * 256 * 128; dst = Wt2 + (size_t)l * 256 * 128; K = 256; OUT = 128; }
    int idx = blockIdx.x * 256 + threadIdx.x;
    if (idx >= K * OUT) return;
    int c = idx / K, k = idx % K;
    dst[idx] = f2bf(src[(size_t)k * OUT + c]);
}

// ---------------- prep: fold BN into scale/shift (all layers, one launch) ----------------
__global__ __launch_bounds__(256) void bnprep_all_kernel(
    const float* __restrict__ be,
    const float* __restrict__ b1, const float* __restrict__ g1, const float* __restrict__ bt1,
    const float* __restrict__ m1, const float* __restrict__ v1,
    const float* __restrict__ b2, const float* __restrict__ g2, const float* __restrict__ bt2,
    const float* __restrict__ m2, const float* __restrict__ v2,
    float* __restrict__ sce, float* __restrict__ she,
    float* __restrict__ sc1, float* __restrict__ sh1,
    float* __restrict__ sc2, float* __restrict__ sh2, int L) {
    int y = blockIdx.x, t = threadIdx.x;
    if (y == 0) {
        if (t < 128) { sce[t] = 1.f; she[t] = be[t]; }
    } else if (y <= L) {
        int o = (y - 1) * 256 + t;
        float s = g1[o] * rsqrtf(v1[o] + BN_EPS);
        sc1[o] = s;
        sh1[o] = (b1[o] - m1[o]) * s + bt1[o];
    } else {
        if (t < 128) {
            int o = (y - L - 1) * 128 + t;
            float s = g2[o] * rsqrtf(v2[o] + BN_EPS);
            sc2[o] = s;
            sh2[o] = (b2[o] - m2[o]) * s + bt2[o];
        }
    }
}

// ---------------- aggregation: h2 = h + sum_{j->i} h[j]   (bf16 in/out, f32 accum) ----------------
__global__ __launch_bounds__(256) void aggregate_kernel(const unsigned short* __restrict__ h,
                                                        const int* __restrict__ row_start,
                                                        const int* __restrict__ csr_src,
                                                        unsigned short* __restrict__ h2, int N) {
    int node = blockIdx.x * 4 + (threadIdx.x >> 6);
    int lane = threadIdx.x & 63;
    if (node >= N) return;
    uint32 s = ((const uint32*)(h + (size_t)node * 128))[lane];
    float a0 = lo_bf(s), a1 = hi_bf(s);
    int rs = row_start[node], re = row_start[node + 1];
    int e = rs;
    for (; e + 4 <= re; e += 4) {
        int s0 = csr_src[e], s1 = csr_src[e + 1], s2 = csr_src[e + 2], s3 = csr_src[e + 3];
        uint32 v0 = ((const uint32*)(h + (size_t)s0 * 128))[lane];
        uint32 v1 = ((const uint32*)(h + (size_t)s1 * 128))[lane];
        uint32 v2 = ((const uint32*)(h + (size_t)s2 * 128))[lane];
        uint32 v3 = ((const uint32*)(h + (size_t)s3 * 128))[lane];
        a0 += (lo_bf(v0) + lo_bf(v1)) + (lo_bf(v2) + lo_bf(v3));
        a1 += (hi_bf(v0) + hi_bf(v1)) + (hi_bf(v2) + hi_bf(v3));
    }
    for (; e < re; ++e) {
        uint32 vv = ((const uint32*)(h + (size_t)csr_src[e] * 128))[lane];
        a0 += lo_bf(vv);
        a1 += hi_bf(vv);
    }
    ((uint32*)(h2 + (size_t)node * 128))[lane] = pack_bf(a0, a1);
}

// ---------------- MFMA GEMM: C = act(A[nrows,K] @ W[K,OUT] * scale + shift) ----------------
// A bf16 (or f32, converted in-register) row-major; Wt bf16 [OUT][K] pre-transposed.
// Swapped operands: lane holds C[r0+(lane&15)][c0+(lane>>4)*4+t] -> packed 8B stores.
template <int K, int OUT, bool RELU, bool A_F32>
__global__ __launch_bounds__(256) void mfma_gemm_kernel(
    const void* __restrict__ Ap, const unsigned short* __restrict__ Wt,
    const float* __restrict__ scale, const float* __restrict__ shift,
    unsigned short* __restrict__ Cout, int nrows)
{
    constexpr int NT = OUT / 16;    // n-tiles of 16 cols
    constexpr int KS = K / 32;      // k-steps of 32
    constexpr int CH = OUT * K / 8; // 16B chunks of Wt
    __shared__ unsigned short WtLds[OUT * K];   // <= 64 KB

    const int tid = threadIdx.x;
    // stage Wt into LDS with XOR swizzle: byte ^= (row&7)<<4  (row = C col)
    {
        const float4* src = (const float4*)Wt;
#pragma unroll
        for (int i = 0; i < CH / 256; ++i) {
            int c = tid + i * 256;
            int row = c / (K / 8);
            unsigned off = ((unsigned)c * 16u) ^ (((unsigned)row & 7u) << 4);
            *(float4*)((char*)WtLds + off) = src[c];
        }
    }
    __syncthreads();

    const int lane = tid & 63;
    const int l15 = lane & 15, lhi = lane >> 4;
    const int r = blockIdx.x * 64 + (tid >> 6) * 16 + l15;
    const int rr = (r < nrows) ? r : (nrows - 1);

    // B-operand fragments: this lane's A row, 8 contiguous bf16 per k-step
    bf16x8 bfrag[KS];
    if constexpr (A_F32) {
        const float* arow = (const float*)Ap + (size_t)rr * K + lhi * 8;
#pragma unroll
        for (int ks = 0; ks < KS; ++ks) {
            float4 u0 = *(const float4*)(arow + ks * 32);
            float4 u1 = *(const float4*)(arow + ks * 32 + 4);
            bf16x8 f;
            f[0] = (short)f2bf(u0.x); f[1] = (short)f2bf(u0.y);
            f[2] = (short)f2bf(u0.z); f[3] = (short)f2bf(u0.w);
            f[4] = (short)f2bf(u1.x); f[5] = (short)f2bf(u1.y);
            f[6] = (short)f2bf(u1.z); f[7] = (short)f2bf(u1.w);
            bfrag[ks] = f;
        }
    } else {
        const unsigned short* arow = (const unsigned short*)Ap + (size_t)rr * K + lhi * 8;
#pragma unroll
        for (int ks = 0; ks < KS; ++ks)
            bfrag[ks] = *(const bf16x8*)(arow + ks * 32);
    }

    f32x4 acc[NT];
#pragma unroll
    for (int nt = 0; nt < NT; ++nt) acc[nt] = (f32x4){0.f, 0.f, 0.f, 0.f};

#pragma unroll
    for (int ks = 0; ks < KS; ++ks) {
#pragma unroll
        for (int nt = 0; nt < NT; ++nt) {
            int row = nt * 16 + l15;
            unsigned off = ((unsigned)((row * K + ks * 32 + lhi * 8) * 2)) ^ (((unsigned)(l15 & 7u)) << 4);
            bf16x8 afrag = *(const bf16x8*)((const char*)WtLds + off);
            acc[nt] = __builtin_amdgcn_mfma_f32_16x16x32_bf16(afrag, bfrag[ks], acc[nt], 0, 0, 0);
        }
    }

    if (r >= nrows) return;
    const float4* sc4 = (const float4*)scale;
    const float4* sh4 = (const float4*)shift;
#pragma unroll
    for (int nt = 0; nt < NT; ++nt) {
        float4 sc = sc4[nt * 4 + lhi];
        float4 sh = sh4[nt * 4 + lhi];
        float y0 = acc[nt][0] * sc.x + sh.x;
        float y1 = acc[nt][1] * sc.y + sh.y;
        float y2 = acc[nt][2] * sc.z + sh.z;
        float y3 = acc[nt][3] * sc.w + sh.w;
        if (RELU) {
            y0 = fmaxf(y0, 0.f); y1 = fmaxf(y1, 0.f);
            y2 = fmaxf(y2, 0.f); y3 = fmaxf(y3, 0.f);
        }
        size_t o = (size_t)r * OUT + nt * 16 + lhi * 4;
        ushort4 p = make_ushort4(f2bf(y0), f2bf(y1), f2bf(y2), f2bf(y3));
        *(ushort4*)(Cout + o) = p;
    }
}

// ---------------- pooling over sorted batch: chunked + boundary atomics ----------------
__global__ __launch_bounds__(128) void pool_kernel(const unsigned short* __restrict__ h,
                                                   const int* __restrict__ batch,
                                                   float* __restrict__ pooled, int N, int chunk) {
    int d = threadIdx.x;
    int start = blockIdx.x * chunk;
    if (start >= N) return;
    int end = min(start + chunk, N);
    float acc = 0.f;
    int g = batch[start];
    for (int r = start; r < end; ++r) {
        int bg = batch[r];
        if (bg != g) {
            atomicAdd(&pooled[g * 128 + d], acc);
            acc = 0.f;
            g = bg;
        }
        acc += bf2f(h[(size_t)r * 128 + d]);
    }
    atomicAdd(&pooled[g * 128 + d], acc);
}

// ---------------- readout MLP ----------------
__global__ __launch_bounds__(128) void readout_kernel(const float* __restrict__ pooled,
                                                      const float* __restrict__ Wr1,
                                                      const float* __restrict__ br1,
                                                      const float* __restrict__ Wr2,
                                                      const float* __restrict__ br2,
                                                      float* __restrict__ out) {
    __shared__ float prow[128];
    __shared__ float t[128];
    int g = blockIdx.x, j = threadIdx.x;
    prow[j] = pooled[g * 128 + j];
    __syncthreads();
    float acc = 0.f;
    for (int k = 0; k < 128; ++k) acc += prow[k] * Wr1[k * 128 + j];
    t[j] = fmaxf(acc + br1[j], 0.f);
    __syncthreads();
    if (j < 10) {
        float a2 = 0.f;
        for (int k = 0; k < 128; ++k) a2 += t[k] * Wr2[k * 10 + j];
        out[g * 10 + j] = a2 + br2[j];
    }
}

extern "C" void kernel_launch(void* const* d_in, const int* in_sizes, int n_in,
                              void* d_out, int out_size, void* d_ws, size_t ws_size,
                              hipStream_t stream) {
    const float* x   = (const float*)d_in[0];
    const int* c2    = (const int*)d_in[1];
    const int* u2    = (const int*)d_in[2];
    const int* batch = (const int*)d_in[3];
    const float* We  = (const float*)d_in[4];
    const float* be  = (const float*)d_in[5];
    const float* W1  = (const float*)d_in[6];
    const float* b1  = (const float*)d_in[7];
    const float* g1  = (const float*)d_in[8];
    const float* bt1 = (const float*)d_in[9];
    const float* m1  = (const float*)d_in[10];
    const float* v1  = (const float*)d_in[11];
    const float* W2  = (const float*)d_in[12];
    const float* b2  = (const float*)d_in[13];
    const float* g2  = (const float*)d_in[14];
    const float* bt2 = (const float*)d_in[15];
    const float* m2  = (const float*)d_in[16];
    const float* v2  = (const float*)d_in[17];
    const float* Wr1 = (const float*)d_in[18];
    const float* br1 = (const float*)d_in[19];
    const float* Wr2 = (const float*)d_in[20];
    const float* br2 = (const float*)d_in[21];

    const int N = in_sizes[3];        // 50000
    const int E = in_sizes[1];        // 800000
    const int L = in_sizes[7] / 256;  // 3
    const int G = out_size / 10;      // 64

    // workspace layout (256B-aligned chunks)
    char* ws = (char*)d_ws;
    size_t off = 0;
    auto alloc = [&](size_t bytes) { char* p = ws + off; off += (bytes + 255) & ~(size_t)255; return p; };
    unsigned short* hb   = (unsigned short*)alloc((size_t)N * 128 * 2);
    unsigned short* h2b  = (unsigned short*)alloc((size_t)N * 128 * 2);
    unsigned short* zb   = (unsigned short*)alloc((size_t)N * 256 * 2);
    unsigned short* Wte  = (unsigned short*)alloc(128 * 128 * 2);
    unsigned short* Wt1  = (unsigned short*)alloc((size_t)L * 256 * 128 * 2);
    unsigned short* Wt2  = (unsigned short*)alloc((size_t)L * 128 * 256 * 2);
    float* sce = (float*)alloc(128 * 4);
    float* she = (float*)alloc(128 * 4);
    float* sc1 = (float*)alloc((size_t)L * 256 * 4);
    float* sh1 = (float*)alloc((size_t)L * 256 * 4);
    float* sc2 = (float*)alloc((size_t)L * 128 * 4);
    float* sh2 = (float*)alloc((size_t)L * 128 * 4);
    float* pooled = (float*)alloc((size_t)G * 128 * 4);
    int* deg      = (int*)alloc((size_t)N * 4);
    int* cursor   = (int*)alloc((size_t)N * 4);
    int* rowstart = (int*)alloc((size_t)(N + 1) * 4);
    int* partials = (int*)alloc(1024 * 4);
    int* csr_src  = (int*)alloc((size_t)E * 4);

    const int scan_blocks = (N + 255) / 256;        // 196
    const int scan_blocks1 = (N + 256) / 256;       // covers n+1

    // ---- CSR build ----
    init_kernel<<<(max(N, G * 128) + 255) / 256, 256, 0, stream>>>(deg, pooled, N, G * 128);
    count_deg_kernel<<<1024, 256, 0, stream>>>(u2, deg, E);
    scan_local_kernel<<<scan_blocks, 256, 0, stream>>>(deg, rowstart, partials, N);
    scan_partials_kernel<<<1, 256, 0, stream>>>(partials, scan_blocks);
    scan_add_kernel<<<scan_blocks1, 256, 0, stream>>>(rowstart, cursor, partials, N, E);
    fill_csr_kernel<<<1024, 256, 0, stream>>>(u2, c2, cursor, csr_src, E);

    // ---- prep: transposes + BN folds ----
    transpose_all_kernel<<<dim3((256 * 128 + 255) / 256, 1 + 2 * L), 256, 0, stream>>>(
        We, W1, W2, Wte, Wt1, Wt2, L);
    bnprep_all_kernel<<<1 + 2 * L, 256, 0, stream>>>(
        be, b1, g1, bt1, m1, v1, b2, g2, bt2, m2, v2, sce, she, sc1, sh1, sc2, sh2, L);

    const int gemm_blocks = (N + 63) / 64;

    // ---- embed: h = x @ We + be  (reads f32 x directly) ----
    mfma_gemm_kernel<128, 128, false, true><<<gemm_blocks, 256, 0, stream>>>(
        x, Wte, sce, she, hb, N);

    // ---- GIN layers ----
    for (int l = 0; l < L; ++l) {
        aggregate_kernel<<<(N + 3) / 4, 256, 0, stream>>>(hb, rowstart, csr_src, h2b, N);
        mfma_gemm_kernel<128, 256, true, false><<<gemm_blocks, 256, 0, stream>>>(
            h2b, Wt1 + (size_t)l * 128 * 256, sc1 + l * 256, sh1 + l * 256, zb, N);
        mfma_gemm_kernel<256, 128, true, false><<<gemm_blocks, 256, 0, stream>>>(
            zb, Wt2 + (size_t)l * 256 * 128, sc2 + l * 128, sh2 + l * 128, hb, N);
    }

    // ---- pooling + readout ----
    const int chunk = (N + 511) / 512;
    pool_kernel<<<512, 128, 0, stream>>>(hb, batch, pooled, N, chunk);
    readout_kernel<<<G, 128, 0, stream>>>(pooled, Wr1, br1, Wr2, br2, (float*)d_out);
}